// Round 19
// baseline (223.417 us; speedup 1.0000x reference)
//
#include <hip/hip_runtime.h>
#include <hip/hip_bf16.h>

typedef __attribute__((ext_vector_type(8))) short sh8;
typedef __attribute__((ext_vector_type(8))) _Float16 h8;
typedef __attribute__((ext_vector_type(4))) float f4;
typedef unsigned short ushort_t;
typedef unsigned int uint_t;

// ---------- fast transcendentals (fp32) ----------
__device__ __forceinline__ float fast_rcp(float x) {
    return __builtin_amdgcn_rcpf(x);
}
__device__ __forceinline__ float sigmoidf_(float x) {
    return fast_rcp(1.f + __expf(-x));
}
__device__ __forceinline__ float tanhf_fast(float x) {
    float ax = fabsf(x);
    float e  = __expf(-2.f * ax);
    float t  = (1.f - e) * fast_rcp(1.f + e);
    return copysignf(t, x);
}

// ---------- fp16 helpers ----------
__device__ __forceinline__ ushort_t f2h(float x) {
    union { _Float16 f; ushort_t u; } cv;
    cv.f = (_Float16)x;
    return cv.u;
}
__device__ __forceinline__ float h2f(ushort_t u) {
    union { _Float16 f; ushort_t u; } cv;
    cv.u = u;
    return (float)cv.f;
}
// XOR swizzle of 8-ushort blocks within a batch-row of sV
__device__ __forceinline__ int swzk(int k, int b) {
    return ((((k >> 3) ^ (b & 7)) << 3) | (k & 7));
}

// ---------- conv1 (1->10, 5x5 VALID) + maxpool2 + tanh ----------
// x: [B,784] as 28x28, out COMPACT fp16: [B,144,10]  (r15/r17 proven)
__global__ __launch_bounds__(256) void conv1_pool_tanh(
    const float* __restrict__ x, const float* __restrict__ w,
    const float* __restrict__ bias, ushort_t* __restrict__ out)
{
    __shared__ float sw[250];
    __shared__ float sb[10];
    int t = threadIdx.x;
    if (t < 250) sw[t] = w[t];
    if (t < 10)  sb[t] = bias[t];
    __syncthreads();

    int gp  = blockIdx.x * 256 + t;
    int b   = gp / 144;
    int pix = gp % 144;
    int py = pix / 12, px = pix % 12;

    const float* img = x + (long)b * 784 + (2 * py) * 28 + 2 * px;
    float r[6][6];
#pragma unroll
    for (int ry = 0; ry < 6; ++ry)
#pragma unroll
        for (int rx = 0; rx < 6; ++rx)
            r[ry][rx] = img[ry * 28 + rx];

    ushort_t* ob = out + ((long)b * 144 + pix) * 10;
    for (int oc = 0; oc < 10; ++oc) {
        float a0 = 0.f, a1 = 0.f, a2 = 0.f, a3 = 0.f;
#pragma unroll
        for (int ky = 0; ky < 5; ++ky)
#pragma unroll
            for (int kx = 0; kx < 5; ++kx) {
                float wv = sw[oc * 25 + ky * 5 + kx];
                a0 += wv * r[ky][kx];
                a1 += wv * r[ky][kx + 1];
                a2 += wv * r[ky + 1][kx];
                a3 += wv * r[ky + 1][kx + 1];
            }
        float m = fmaxf(fmaxf(a0, a1), fmaxf(a2, a3)) + sb[oc];
        ob[oc] = f2h(tanhf_fast(m));
    }
}

// ---------- m1: row-pinned waves, unit-major rows, in-register epilogue ----
// x fp16 [B,H*H,CIN]; wfm unit-major fp16 A-frags; bias fp32; out fp16.
// Wave w owns grid row w (cell (w, d-w) at step d). MFMA C-layout delivers
// gates 0-3 of unit t*4+lg into acc[t][0..3]; g4 via wave-private f32 relay
// (validated r13). h stores via LDS relay -> coalesced (fixes r13 failure).
// sV parity-buffered, c_left in registers, c_up via parity sCup:
// ONE barrier per step.
template<int H, int HID, int CIN, int KV, int NK>
__global__ __launch_bounds__(H * 64, 3) void mdlstm_rowreg(
    const ushort_t* __restrict__ x, const short* __restrict__ wfm,
    const float* __restrict__ bias, ushort_t* __restrict__ out)
{
    constexpr int N   = H * H;
    constexpr int NT  = H * 64;
    constexpr int NB  = 16;
    constexpr int HL0 = CIN, HU0 = CIN + HID;
    constexpr int T03 = (4 * HID) / 16;        // gate0-3 tiles
    constexpr int G4T = (HID + 15) / 16;       // g4 tiles
    constexpr int TT  = T03 + G4T;
    constexpr int UPT = HID / 4;               // units per thread
    constexpr int XLD = (NB * CIN + 63) / 64;
    static_assert((4 * HID) % 16 == 0, "gate rows align");
    static_assert(HID % 4 == 0, "units per lg");
    static_assert(NK * 32 == KV, "K chain covers KV");
    static_assert(KV >= CIN + 2 * HID, "V fits");
    static_assert(UPT * 64 == NB * HID, "store pass exact");

    __shared__ ushort_t sV[2][H][NB][KV];      // fp16 V, parity buffered
    __shared__ float    sCup[2][H][NB][HID];   // c relay, parity buffered
    __shared__ float    sG4[H][NB][HID];       // g4 relay (wave-private row)
    __shared__ ushort_t sHout[H][NB][HID];     // h relay for coalesced store

    const int tid  = threadIdx.x;
    const int lane = tid & 63;
    const int w    = tid >> 6;                 // row
    const int lr   = lane & 15;                // batch / B-col
    const int lg   = lane >> 4;
    const long bB  = (long)blockIdx.x * NB;

    // ---- A-frags: coalesced loads from precomputed frag buffer ----
    h8 Af[TT][NK];
    {
        const h8* wv = (const h8*)wfm;
#pragma unroll
        for (int t = 0; t < TT; ++t)
#pragma unroll
            for (int ks = 0; ks < NK; ++ks)
                Af[t][ks] = wv[(t * NK + ks) * 64 + lane];
    }
    // bias in unit-major row order
    f4 biasF[TT];
#pragma unroll
    for (int t = 0; t < TT; ++t)
#pragma unroll
        for (int q = 0; q < 4; ++q) {
            int r = t * 16 + lg * 4 + q;
            float bv = 0.f;
            if (r < 4 * HID)      bv = bias[(r & 3) * HID + (r >> 2)];
            else if (r < 5 * HID) bv = bias[r];
            biasF[t][q] = bv;
        }

    // ---- zero sV (both parities); stage x of cell (0,0) ----
    for (int idx = tid; idx < 2 * H * NB * KV; idx += NT)
        (&sV[0][0][0][0])[idx] = 0;
    __syncthreads();
    for (int idx = tid; idx < NB * CIN; idx += NT) {
        int b = idx / CIN, c = idx % CIN;
        sV[0][0][b][swzk(c, b)] = x[(bB + b) * (long)(N * CIN) + c];
    }
    __syncthreads();

    // ---- hoisted x-load decomposition (per-lane constants) ----
    int  xb2[XLD], xoff[XLD];
    long xgb[XLD];
    bool xok[XLD];
#pragma unroll
    for (int q = 0; q < XLD; ++q) {
        int idx = q * 64 + lane;
        xok[q] = idx < NB * CIN;
        int b2 = 0, c2 = 0;
        if (xok[q]) { b2 = idx / CIN; c2 = idx % CIN; }
        xb2[q]  = b2;
        xoff[q] = swzk(c2, b2);
        xgb[q]  = (bB + b2) * (long)(N * CIN) + c2;
    }
    // hoisted per-unit sV offsets
    int svl[UPT], svu[UPT];
#pragma unroll
    for (int t = 0; t < UPT; ++t) {
        int j = t * 4 + lg;
        svl[t] = swzk(HL0 + j, lr);
        svu[t] = swzk(HU0 + j, lr);
    }
    float creg[UPT];
#pragma unroll
    for (int u = 0; u < UPT; ++u) creg[u] = 0.f;

    // ---- diagonal loop: ONE barrier per step ----
    for (int d = 0; d < 2 * H - 1; ++d) {
        const int par = d & 1;
        const int jc  = d - w;
        const int jn  = jc + 1;
        const bool act  = (unsigned)jc < (unsigned)H;
        const bool actn = (unsigned)jn < (unsigned)H;

        // early x loads for this row's next cell (latency hides under MFMA)
        ushort_t xr[XLD];
        if (actn) {
            const int co = (w * H + jn) * CIN;
#pragma unroll
            for (int q = 0; q < XLD; ++q)
                if (xok[q]) xr[q] = x[xgb[q] + co];
        }

        if (act) {
            // ===== gates (fp16 MFMA) =====
            h8 Bh[NK];
#pragma unroll
            for (int ks = 0; ks < NK; ++ks) {
                const int bo = (((ks * 4 + lg) ^ (lr & 7)) << 3);
                Bh[ks] = *(const h8*)&sV[par][w][lr][bo];
            }
            f4 acc[TT];
#pragma unroll
            for (int t = 0; t < TT; ++t) {
                acc[t] = __builtin_amdgcn_mfma_f32_16x16x32_f16(
                             Af[t][0], Bh[0], biasF[t], 0, 0, 0);
#pragma unroll
                for (int ks = 1; ks < NK; ++ks)
                    acc[t] = __builtin_amdgcn_mfma_f32_16x16x32_f16(
                                 Af[t][ks], Bh[ks], acc[t], 0, 0, 0);
            }
            // ===== g4 relay (wave-private, program-order safe) =====
#pragma unroll
            for (int g = 0; g < G4T; ++g)
#pragma unroll
                for (int q = 0; q < 4; ++q) {
                    int u = g * 16 + lg * 4 + q;
                    if (u < HID) sG4[w][lr][u] = acc[T03 + g][q];
                }
            // ===== in-register epilogue =====
            const int cellOff = (w * H + jc) * HID;
#pragma unroll
            for (int t = 0; t < UPT; ++t) {
                const int j = t * 4 + lg;
                float g4 = sG4[w][lr][j];
                float g0 = acc[t][0], g1 = acc[t][1];
                float g2 = acc[t][2], g3 = acc[t][3];
                float c_left = (jc > 0) ? creg[t] : 0.f;
                float c_up   = (w > 0) ? sCup[par][w - 1][lr][j] : 0.f;
                float cc = sigmoidf_(g1) * c_left + sigmoidf_(g2) * c_up
                         + sigmoidf_(g0) * tanhf_fast(g4);
                float hh = sigmoidf_(g3) * tanhf_fast(cc);
                creg[t] = cc;
                sCup[par ^ 1][w][lr][j] = cc;
                ushort_t hv = f2h(hh);
                if (jn < H)    sV[par ^ 1][w][lr][svl[t]]     = hv;
                if (w + 1 < H) sV[par ^ 1][w + 1][lr][svu[t]] = hv;
                sHout[w][lr][j] = hv;
            }
            // ===== coalesced store pass (wave-local) =====
#pragma unroll
            for (int q = 0; q < UPT; ++q) {
                int f = q * 64 + lane;
                int b2 = f / HID, j2 = f % HID;
                out[(bB + b2) * (long)(N * HID) + cellOff + j2] =
                    sHout[w][b2][j2];
            }
        }
        // write prefetched x into next-parity V
        if (actn) {
#pragma unroll
            for (int q = 0; q < XLD; ++q)
                if (xok[q]) sV[par ^ 1][w][xb2[q]][xoff[q]] = xr[q];
        }
        __syncthreads();
    }
}

// ---------- diagonal-wavefront fp16-MFMA 2D-LSTM, fat waves (m2) ----------
template<int H, int HID, int CIN, int KV, int NK, int NWM, int CSPL, int TPW, int NB>
__global__ __launch_bounds__(NWM * CSPL * 64) void mdlstm_f16(
    const ushort_t* __restrict__ x, const short* __restrict__ wfm,
    const float* __restrict__ bias, ushort_t* __restrict__ out)
{
    constexpr int N    = H * H;
    constexpr int NT   = NWM * CSPL * 64;
    constexpr int HL0  = CIN, HU0 = CIN + HID;
    constexpr int SVS  = KV;
    constexpr int GS   = 5 * HID;
    constexpr int XTOT = H * NB * CIN;
    constexpr int XMAX = (XTOT + NT - 1) / NT;
    constexpr int EPT  = NB * HID;
    constexpr int CPB  = NT / EPT;
    static_assert(NWM * TPW * 16 >= 5 * HID, "tiles cover gate rows");
    static_assert(KV >= CIN + 2 * HID, "K covers V");
    static_assert(CPB >= 1, "epilogue coverage");

    __shared__ ushort_t sV[H][16][SVS];
    __shared__ float    sG[H][NB][GS];
    __shared__ float    sC[2][H][NB][HID];

    const int tid  = threadIdx.x;
    const int lane = tid & 63;
    const int wid  = tid >> 6;
    const int mth  = wid % NWM;
    const int cs   = wid / NWM;
    const int lr   = lane & 15;
    const int lg   = lane >> 4;
    const long bB  = (long)blockIdx.x * NB;

    h8 Af[TPW][NK];
    {
        const h8* wv = (const h8*)wfm;
#pragma unroll
        for (int tt = 0; tt < TPW; ++tt)
#pragma unroll
            for (int ks = 0; ks < NK; ++ks)
                Af[tt][ks] = wv[((mth * TPW + tt) * NK + ks) * 64 + lane];
    }

    f4 biasF[TPW];
#pragma unroll
    for (int tt = 0; tt < TPW; ++tt)
#pragma unroll
        for (int q = 0; q < 4; ++q) {
            int rr = (mth * TPW + tt) * 16 + lg * 4 + q;
            biasF[tt][q] = (rr < 5 * HID) ? bias[rr] : 0.f;
        }

    for (int idx = tid; idx < H * 16 * SVS; idx += NT) (&sV[0][0][0])[idx] = 0;
    __syncthreads();
    for (int idx = tid; idx < NB * CIN; idx += NT) {
        int b = idx / CIN, c = idx % CIN;
        sV[0][b][swzk(c, b)] = x[(bB + b) * (long)(N * CIN) + c];
    }
    __syncthreads();

    const bool ep_act = tid < CPB * EPT;
    const int  ep_ci0 = tid / EPT;
    const int  ep_b   = (tid % EPT) / HID;
    const int  ep_j   = tid % HID;
    const int  svl    = swzk(HL0 + ep_j, ep_b);
    const int  svu    = swzk(HU0 + ep_j, ep_b);
    ushort_t* outb = out + (bB + ep_b) * (long)(N * HID) + ep_j;

    int  xq_ci[XMAX], xq_b[XMAX], xq_off[XMAX];
    long xq_gb[XMAX];
    bool xq_ok[XMAX];
#pragma unroll
    for (int q = 0; q < XMAX; ++q) {
        int idx = tid + q * NT;
        xq_ok[q] = (idx < XTOT);
        int ci = 0, b = 0, c = 0;
        if (xq_ok[q]) { ci = idx / (NB * CIN); int rem = idx % (NB * CIN);
                        b = rem / CIN; c = rem % CIN; }
        xq_ci[q]  = ci; xq_b[q] = b;
        xq_off[q] = swzk(c, b);
        xq_gb[q]  = (bB + b) * (long)(N * CIN) + c;
    }

    for (int d = 0; d < 2 * H - 1; ++d) {
        const int i0  = (d > H - 1) ? d - (H - 1) : 0;
        const int i1  = (d < H - 1) ? d : H - 1;
        const int nc  = i1 - i0 + 1;
        const int i0n = (d + 1 > H - 1) ? d + 1 - (H - 1) : 0;
        const int i1n = (d + 1 < H - 1) ? d + 1 : H - 1;
        const int ncn = (d + 1 < 2 * H - 1) ? (i1n - i0n + 1) : 0;
        const int par = d & 1;

        for (int ci = cs; ci < nc; ci += CSPL) {
            h8 Bh[NK];
#pragma unroll
            for (int ks = 0; ks < NK; ++ks) {
                const int bo = (((ks * 4 + lg) ^ (lr & 7)) << 3);
                Bh[ks] = *(const h8*)&sV[ci][lr][bo];
            }
            f4 acc[TPW];
#pragma unroll
            for (int tt = 0; tt < TPW; ++tt) {
                acc[tt] = __builtin_amdgcn_mfma_f32_16x16x32_f16(
                              Af[tt][0], Bh[0], biasF[tt], 0, 0, 0);
#pragma unroll
                for (int ks = 1; ks < NK; ++ks)
                    acc[tt] = __builtin_amdgcn_mfma_f32_16x16x32_f16(
                                  Af[tt][ks], Bh[ks], acc[tt], 0, 0, 0);
            }
#pragma unroll
            for (int tt = 0; tt < TPW; ++tt) {
                int row4 = (mth * TPW + tt) * 16 + lg * 4;
                if (lr < NB && row4 + 4 <= 5 * HID)
                    *(f4*)&sG[ci][lr][row4] = acc[tt];
            }
        }

        ushort_t xval[XMAX];
#pragma unroll
        for (int q = 0; q < XMAX; ++q)
            if (xq_ok[q] && xq_ci[q] < ncn) {
                int ii = i0n + xq_ci[q];
                xval[q] = x[xq_gb[q] + (long)(ii * H + (d + 1 - ii)) * CIN];
            }
        __syncthreads();

        if (ep_act) {
            for (int ci = ep_ci0; ci < nc; ci += CPB) {
                const int i = i0 + ci, jc = d - i;
                const float* gp = &sG[ci][ep_b][ep_j];
                float g0 = gp[0],       g1 = gp[HID],     g2 = gp[2 * HID];
                float g3 = gp[3 * HID], g4 = gp[4 * HID];
                float c_left = (jc > 0) ? sC[par][i][ep_b][ep_j] : 0.f;
                float c_up   = (i  > 0) ? sC[par][i - 1][ep_b][ep_j] : 0.f;
                float cc = sigmoidf_(g1) * c_left + sigmoidf_(g2) * c_up
                         + sigmoidf_(g0) * tanhf_fast(g4);
                float hh = sigmoidf_(g3) * tanhf_fast(cc);
                sC[par ^ 1][i][ep_b][ep_j] = cc;
                ushort_t hv = f2h(hh);
                if (jc + 1 < H) sV[i - i0n][ep_b][svl]     = hv;
                if (i + 1 < H)  sV[i + 1 - i0n][ep_b][svu] = hv;
                outb[(i * H + jc) * HID] = hv;
            }
        }
#pragma unroll
        for (int q = 0; q < XMAX; ++q)
            if (xq_ok[q] && xq_ci[q] < ncn)
                sV[xq_ci[q]][xq_b[q]][xq_off[q]] = xval[q];
        __syncthreads();
    }
}

// ---------- merged prep: all weight fragments ----------
// conv2/fc1: fp16 wh/wl frags. m1: UNIT-MAJOR fp16 frags. m2: fp16 frags.
__global__ __launch_bounds__(256) void prep_frags(
    const float* __restrict__ wt,  short* __restrict__ wf,
    const float* __restrict__ w1,  short* __restrict__ wf1,
    const float* __restrict__ m1Wx, const float* __restrict__ m1Wl,
    const float* __restrict__ m1Wu, short* __restrict__ wfm1,
    const float* __restrict__ m2Wx, const float* __restrict__ m2Wl,
    const float* __restrict__ m2Wu, short* __restrict__ wfm2)
{
    int gid = blockIdx.x * 256 + threadIdx.x;
    if (gid < 25600) {                      // ---- conv2 frags ----
        int id = gid;
        int e    = id & 7;
        int lane = (id >> 3) & 63;
        int m    = (id >> 9) & 1;
        int tt   = id >> 10;            // tx*5+ty
        int tx = tt / 5, ty = tt % 5;
        int c = lane & 15, kg = lane >> 4;
        int oc = m * 16 + c, ic = kg * 8 + e;
        float wv = (oc < 30 && ic < 20)
                 ? wt[((oc * 20 + ic) * 5 + ty) * 5 + tx] : 0.f;
        ushort_t wh = f2h(wv);
        ushort_t wl = f2h(wv - h2f(wh));
        wf[(((tt * 2 + m) * 2 + 0) * 64 + lane) * 8 + e] = (short)wh;
        wf[(((tt * 2 + m) * 2 + 1) * 64 + lane) * 8 + e] = (short)wl;
    } else if (gid < 25600 + 143360) {      // ---- fc1 frags ----
        int id = gid - 25600;
        int e    = id & 7;
        int r    = id >> 3;
        int lane = r & 63;  r >>= 6;
        int h    = r & 1;   r >>= 1;
        int ks   = r % 20;
        int m    = r / 20;
        int o  = m * 16 + (lane & 15);
        int kp = ks * 32 + (lane >> 4) * 8 + e;
        int pix = kp / 40, hid = kp % 40;
        float wv = (o < 100) ? w1[o * 640 + hid * 16 + pix] : 0.f;
        ushort_t wh = f2h(wv);
        ushort_t v  = h ? f2h(wv - h2f(wh)) : wh;
        wf1[id] = (short)v;
    } else if (gid < 25600 + 143360 + 7168) {   // ---- m1 frags (unit-major) --
        // HID=20, CIN=10, NK=2; new row 4j+p (p=gate 0..3), g4 at rows 80..99
        int id = gid - (25600 + 143360);
        int e    = id & 7;
        int lane = (id >> 3) & 63;
        int r    = id >> 9;
        int ks   = r & 1;
        int t    = r >> 1;              // 0..6
        int rg = t * 16 + (lane & 15);  // unit-major row
        int k  = ks * 32 + (lane >> 4) * 8 + e;
        int orig = -1;
        if (rg < 80)       orig = (rg & 3) * 20 + (rg >> 2);
        else if (rg < 100) orig = rg;
        float wv = 0.f;
        if (orig >= 0) {
            if (k < 10)       wv = m1Wx[orig * 10 + k];
            else if (k < 30)  wv = m1Wl[orig * 20 + (k - 10)];
            else if (k < 50)  wv = m1Wu[orig * 20 + (k - 30)];
        }
        wfm1[id] = (short)f2h(wv);
    } else if (gid < 25600 + 143360 + 7168 + 30720) {  // ---- m2 frags ----
        int id = gid - (25600 + 143360 + 7168);
        int e    = id & 7;
        int lane = (id >> 3) & 63;
        int r    = id >> 9;             // (mth*5+tt)*4+ks
        int ks   = r & 3;
        int q    = r >> 2;
        int tt   = q % 5;
        int mth  = q / 5;
        int rg = (mth * 5 + tt) * 16 + (lane & 15);
        int k  = ks * 32 + (lane >> 4) * 8 + e;
        float wv = 0.f;
        if (rg < 200) {
            if (k < 30)        wv = m2Wx[rg * 30 + k];
            else if (k < 70)   wv = m2Wl[rg * 40 + (k - 30)];
            else if (k < 110)  wv = m2Wu[rg * 40 + (k - 70)];
        }
        wfm2[id] = (short)f2h(wv);
    }
}

// ---------- conv2 via tap-decomposed MFMA, fp16 input, 16 images/block ----
__global__ __launch_bounds__(320, 2) void conv2_mfma(
    const ushort_t* __restrict__ in, const short* __restrict__ wf,
    const float* __restrict__ bias, ushort_t* __restrict__ out)
{
    constexpr int NIMG = 16;
    __shared__ ushort_t sImg[2][144][40];
    __shared__ float    sPart[5][2][4][16][20];
    __shared__ float    sB[30];

    const int tid  = threadIdx.x;
    const int lane = tid & 63;
    const int wid  = tid >> 6;          // = tx
    const int c    = lane & 15;
    const int kg   = lane >> 4;
    const long b0  = (long)blockIdx.x * NIMG;

    const h8* wfv = (const h8*)wf;
    h8 Awh[5][2], Awl[5][2];
#pragma unroll
    for (int ty = 0; ty < 5; ++ty)
#pragma unroll
        for (int m = 0; m < 2; ++m) {
            int base = (((wid * 5 + ty) * 2 + m) * 2) * 64 + lane;
            Awh[ty][m] = wfv[base];
            Awl[ty][m] = wfv[base + 64];
        }

    for (int idx = tid; idx < 2 * 144 * 20; idx += 320) {
        int bb = idx / (144 * 20);
        int r  = idx % (144 * 20);
        sImg[bb][r / 20][20 + r % 20] = 0;
    }
    if (tid < 30) sB[tid] = bias[tid];

    {
        const ushort_t* p = in + b0 * 2880;
        uint2 u0 = *(const uint2*)(p + 4 * tid);
        uint2 u1 = *(const uint2*)(p + 4 * (tid + 320));
        uint2 u2 = {0, 0};
        if (tid < 80) u2 = *(const uint2*)(p + 4 * (tid + 640));
        {
            int g = 4 * tid;          *(uint2*)&sImg[0][g / 20][g % 20] = u0;
            g = 4 * (tid + 320);      *(uint2*)&sImg[0][g / 20][g % 20] = u1;
            if (tid < 80) { g = 4 * (tid + 640);
                            *(uint2*)&sImg[0][g / 20][g % 20] = u2; }
        }
    }
    __syncthreads();

    const int y0 = c >> 3, x = c & 7;
    for (int img = 0; img < NIMG; ++img) {
        const int cb = img & 1;
        uint2 u0, u1, u2;
        const bool have = (img + 1 < NIMG);
        if (have) {
            const ushort_t* p = in + (b0 + img + 1) * 2880;
            u0 = *(const uint2*)(p + 4 * tid);
            u1 = *(const uint2*)(p + 4 * (tid + 320));
            if (tid < 80) u2 = *(const uint2*)(p + 4 * (tid + 640));
        }
#pragma unroll
        for (int p4 = 0; p4 < 4; ++p4) {
            const int pos = (2 * p4 + y0) * 12 + x + wid;
            const ushort_t* bh = &sImg[cb][pos][kg * 8];
            f4 aH0 = {0.f,0.f,0.f,0.f}, aL0 = {0.f,0.f,0.f,0.f};
            f4 aH1 = {0.f,0.f,0.f,0.f}, aL1 = {0.f,0.f,0.f,0.f};
#pragma unroll
            for (int ks = 0; ks < 5; ++ks) {
                h8 Bh = *(const h8*)(bh + ks * 12 * 40);
                aH0 = __builtin_amdgcn_mfma_f32_16x16x32_f16(Awh[ks][0], Bh, aH0, 0, 0, 0);
                aL0 = __builtin_amdgcn_mfma_f32_16x16x32_f16(Awl[ks][0], Bh, aL0, 0, 0, 0);
                aH1 = __builtin_amdgcn_mfma_f32_16x16x32_f16(Awh[ks][1], Bh, aH1, 0, 0, 0);
                aL1 = __builtin_amdgcn_mfma_f32_16x16x32_f16(Awl[ks][1], Bh, aL1, 0, 0, 0);
            }
            f4 c0 = aH0 + aL0;
            f4 c1 = aH1 + aL1;
            *(f4*)&sPart[wid][0][p4][c][kg * 4] = c0;
            *(f4*)&sPart[wid][1][p4][c][kg * 4] = c1;
        }
        if (have) {
            int g = 4 * tid;          *(uint2*)&sImg[cb ^ 1][g / 20][g % 20] = u0;
            g = 4 * (tid + 320);      *(uint2*)&sImg[cb ^ 1][g / 20][g % 20] = u1;
            if (tid < 80) { g = 4 * (tid + 640);
                            *(uint2*)&sImg[cb ^ 1][g / 20][g % 20] = u2; }
        }
        __syncthreads();
        for (int idx = tid; idx < 480; idx += 320) {
            int pix = idx / 30, oc = idx % 30;
            int m = oc >> 4, r = oc & 15;
            int py = pix >> 2, px = pix & 3;
            float vmax = -1e30f;
#pragma unroll
            for (int dy = 0; dy < 2; ++dy)
#pragma unroll
                for (int dx = 0; dx < 2; ++dx) {
                    int n = (2 * py + dy) * 8 + 2 * px + dx;
                    float s = 0.f;
#pragma unroll
                    for (int w = 0; w < 5; ++w)
                        s += sPart[w][m][n >> 4][n & 15][r];
                    vmax = fmaxf(vmax, s);
                }
            out[(b0 + img) * 480 + idx] = f2h(tanhf_fast(vmax + sB[oc]));
        }
        __syncthreads();
    }
}

// ---------- fused fc1(640->100)+tanh + fc2(100->10) + softmax ----------
__global__ __launch_bounds__(448) void fc_fused(
    const ushort_t* __restrict__ in, const short* __restrict__ wf1,
    const float* __restrict__ b1, const float* __restrict__ w2,
    const float* __restrict__ b2, float* __restrict__ out)
{
    constexpr int XS = 648;
    __shared__ ushort_t sX[16][XS];
    __shared__ float    sG[16][116];
    __shared__ float    sF[16][101];
    __shared__ float    sW2[1000];
    __shared__ float    sB2[10];
    __shared__ float    sL[16][12];

    const int tid  = threadIdx.x;
    const int lane = tid & 63;
    const int wid  = tid >> 6;
    const int lr   = lane & 15;
    const int lg   = lane >> 4;
    const long b0  = (long)blockIdx.x * 16;

    for (int idx = tid; idx < 2560; idx += 448) {
        int flat = idx * 4;
        int row = flat / 640, col = flat % 640;
        *(uint2*)&sX[row][col] =
            *(const uint2*)(in + (b0 + row) * 640 + col);
    }
    for (int idx = tid; idx < 1000; idx += 448) sW2[idx] = w2[idx];
    if (tid < 10) sB2[tid] = b2[tid];

    f4 biasF;
#pragma unroll
    for (int q = 0; q < 4; ++q) {
        int rr = wid * 16 + lg * 4 + q;
        biasF[q] = (rr < 100) ? b1[rr] : 0.f;
    }
    __syncthreads();

    {
        const h8* wfv = (const h8*)wf1;
        f4 hh = biasF, ll = {0.f, 0.f, 0.f, 0.f};
#pragma unroll
        for (int ks = 0; ks < 20; ++ks) {
            int base = ((wid * 20 + ks) * 2) * 64 + lane;
            h8 Awh = wfv[base];
            h8 Awl = wfv[base + 64];
            h8 Bh  = *(const h8*)&sX[lr][ks * 32 + lg * 8];
            hh = __builtin_amdgcn_mfma_f32_16x16x32_f16(Awh, Bh, hh, 0, 0, 0);
            ll = __builtin_amdgcn_mfma_f32_16x16x32_f16(Awl, Bh, ll, 0, 0, 0);
        }
        f4 acc = hh + ll;
        *(f4*)&sG[lr][wid * 16 + lg * 4] = acc;
    }
    __syncthreads();

    for (int idx = tid; idx < 1600; idx += 448) {
        int bb = idx / 100, o = idx % 100;
        sF[bb][o] = tanhf_fast(sG[bb][o]);
    }
    __syncthreads();

    if (tid < 160) {
        int o2 = tid >> 4, bb = tid & 15;
        const float* wr = &sW2[o2 * 100];
        float acc = sB2[o2];
        for (int k = 0; k < 100; ++k) acc += sF[bb][k] * wr[k];
        sL[bb][o2] = acc;
    }
    __syncthreads();

    if (tid < 16) {
        float lg10[10];
#pragma unroll
        for (int o = 0; o < 10; ++o) lg10[o] = sL[tid][o];
        float m = lg10[0];
#pragma unroll
        for (int o = 1; o < 10; ++o) m = fmaxf(m, lg10[o]);
        float s = 0.f;
#pragma unroll
        for (int o = 0; o < 10; ++o) { lg10[o] = __expf(lg10[o] - m); s += lg10[o]; }
        float inv = fast_rcp(s);
        float* ob = out + (b0 + tid) * 10;
#pragma unroll
        for (int o = 0; o < 10; ++o) ob[o] = lg10[o] * inv;
    }
}

extern "C" void kernel_launch(void* const* d_in, const int* in_sizes, int n_in,
                              void* d_out, int out_size, void* d_ws, size_t ws_size,
                              hipStream_t stream)
{
    const float* x    = (const float*)d_in[0];
    const float* c1w  = (const float*)d_in[1];
    const float* c1b  = (const float*)d_in[2];
    const float* m1Wx = (const float*)d_in[3];
    const float* m1Wl = (const float*)d_in[4];
    const float* m1Wu = (const float*)d_in[5];
    const float* m1b  = (const float*)d_in[6];
    const float* c2w  = (const float*)d_in[7];
    const float* c2b  = (const float*)d_in[8];
    const float* m2Wx = (const float*)d_in[9];
    const float* m2Wl = (const float*)d_in[10];
    const float* m2Wu = (const float*)d_in[11];
    const float* m2b  = (const float*)d_in[12];
    const float* f1w  = (const float*)d_in[13];
    const float* f1b  = (const float*)d_in[14];
    const float* f2w  = (const float*)d_in[15];
    const float* f2b  = (const float*)d_in[16];
    float* outp = (float*)d_out;

    char* ws = (char*)d_ws;
    ushort_t* a1 = (ushort_t*)ws;                  // [B,144,10] fp16 11.8 MB
    ushort_t* h1 = (ushort_t*)(ws + 23592960);     // [B,144,20] fp16 11.8 MB
    ushort_t* a2 = a1;                             // [B,16,30] fp16
    ushort_t* h2 = h1;                             // [B,640] fp16 reuse
    short* wfrag  = (short*)(ws + 50331648);       // conv2 frags
    short* wfrag1 = (short*)(ws + 51380224);       // fc1 frags
    short* wfm1   = (short*)(ws + 52428800);       // m1 frags (unit-major)
    short* wfm2   = (short*)(ws + 53477376);       // m2 frags

    prep_frags<<<808, 256, 0, stream>>>(c2w, wfrag, f1w, wfrag1,
                                        m1Wx, m1Wl, m1Wu, wfm1,
                                        m2Wx, m2Wl, m2Wu, wfm2);
    conv1_pool_tanh<<<2304, 256, 0, stream>>>(x, c1w, c1b, a1);
    // m1: row-pinned in-register-epilogue kernel
    mdlstm_rowreg<12, 20, 10, 64, 2><<<256, 768, 0, stream>>>(
        a1, wfm1, m1b, h1);
    conv2_mfma<<<256, 320, 0, stream>>>(h1, wfrag, c2b, a2);
    // m2: H=4, HID=40, CIN=30, KV=128, NK=4, NWM=3, CSPL=4, TPW=5, NB=16
    mdlstm_f16<4, 40, 30, 128, 4, 3, 4, 5, 16><<<256, 768, 0, stream>>>(
        a2, wfm2, m2b, h2);
    fc_fused<<<256, 448, 0, stream>>>(h2, wfrag1, f1b, f2w, f2b, outp);
}

// Round 20
// 149.672 us; speedup vs baseline: 1.4927x; 1.4927x over previous
//
#include <hip/hip_runtime.h>
#include <hip/hip_bf16.h>

typedef __attribute__((ext_vector_type(8))) short sh8;
typedef __attribute__((ext_vector_type(8))) _Float16 h8;
typedef __attribute__((ext_vector_type(4))) float f4;
typedef unsigned short ushort_t;
typedef unsigned int uint_t;

// ---------- fast transcendentals (fp32) ----------
__device__ __forceinline__ float fast_rcp(float x) {
    return __builtin_amdgcn_rcpf(x);
}
__device__ __forceinline__ float sigmoidf_(float x) {
    return fast_rcp(1.f + __expf(-x));
}
__device__ __forceinline__ float tanhf_fast(float x) {
    float ax = fabsf(x);
    float e  = __expf(-2.f * ax);
    float t  = (1.f - e) * fast_rcp(1.f + e);
    return copysignf(t, x);
}

// ---------- fp16 helpers ----------
__device__ __forceinline__ ushort_t f2h(float x) {
    union { _Float16 f; ushort_t u; } cv;
    cv.f = (_Float16)x;
    return cv.u;
}
__device__ __forceinline__ float h2f(ushort_t u) {
    union { _Float16 f; ushort_t u; } cv;
    cv.u = u;
    return (float)cv.f;
}
// XOR swizzle of 8-ushort blocks within a batch-row of sV
__device__ __forceinline__ int swzk(int k, int b) {
    return ((((k >> 3) ^ (b & 7)) << 3) | (k & 7));
}

// ---------- conv1 (1->10, 5x5 VALID) + maxpool2 + tanh ----------
// x: [B,784] as 28x28, out COMPACT fp16: [B,144,10]  (r15/r17 proven)
__global__ __launch_bounds__(256) void conv1_pool_tanh(
    const float* __restrict__ x, const float* __restrict__ w,
    const float* __restrict__ bias, ushort_t* __restrict__ out)
{
    __shared__ float sw[250];
    __shared__ float sb[10];
    int t = threadIdx.x;
    if (t < 250) sw[t] = w[t];
    if (t < 10)  sb[t] = bias[t];
    __syncthreads();

    int gp  = blockIdx.x * 256 + t;
    int b   = gp / 144;
    int pix = gp % 144;
    int py = pix / 12, px = pix % 12;

    const float* img = x + (long)b * 784 + (2 * py) * 28 + 2 * px;
    float r[6][6];
#pragma unroll
    for (int ry = 0; ry < 6; ++ry)
#pragma unroll
        for (int rx = 0; rx < 6; ++rx)
            r[ry][rx] = img[ry * 28 + rx];

    ushort_t* ob = out + ((long)b * 144 + pix) * 10;
    for (int oc = 0; oc < 10; ++oc) {
        float a0 = 0.f, a1 = 0.f, a2 = 0.f, a3 = 0.f;
#pragma unroll
        for (int ky = 0; ky < 5; ++ky)
#pragma unroll
            for (int kx = 0; kx < 5; ++kx) {
                float wv = sw[oc * 25 + ky * 5 + kx];
                a0 += wv * r[ky][kx];
                a1 += wv * r[ky][kx + 1];
                a2 += wv * r[ky + 1][kx];
                a3 += wv * r[ky + 1][kx + 1];
            }
        float m = fmaxf(fmaxf(a0, a1), fmaxf(a2, a3)) + sb[oc];
        ob[oc] = f2h(tanhf_fast(m));
    }
}

// ---------- diagonal-wavefront fp16-MFMA 2D-LSTM, fat waves ----------
// x compact fp16 [B, H*H, CIN]; wfm = precomputed fp16 A-frags; bias fp32;
// out fp16 [B,H*H,HID].  (r18 proven)
template<int H, int HID, int CIN, int KV, int NK, int NWM, int CSPL, int TPW, int NB>
__global__ __launch_bounds__(NWM * CSPL * 64) void mdlstm_f16(
    const ushort_t* __restrict__ x, const short* __restrict__ wfm,
    const float* __restrict__ bias, ushort_t* __restrict__ out)
{
    constexpr int N    = H * H;
    constexpr int NT   = NWM * CSPL * 64;
    constexpr int HL0  = CIN, HU0 = CIN + HID;
    constexpr int SVS  = KV;
    constexpr int GS   = 5 * HID;
    constexpr int XTOT = H * NB * CIN;
    constexpr int XMAX = (XTOT + NT - 1) / NT;
    constexpr int EPT  = NB * HID;
    constexpr int CPB  = NT / EPT;
    static_assert(NWM * TPW * 16 >= 5 * HID, "tiles cover gate rows");
    static_assert(KV >= CIN + 2 * HID, "K covers V");
    static_assert(CPB >= 1, "epilogue coverage");

    __shared__ ushort_t sV[H][16][SVS];      // fp16 V
    __shared__ float    sG[H][NB][GS];       // gates [slot][batch][row]
    __shared__ float    sC[2][H][NB][HID];   // c-state, parity buffered

    const int tid  = threadIdx.x;
    const int lane = tid & 63;
    const int wid  = tid >> 6;
    const int mth  = wid % NWM;
    const int cs   = wid / NWM;
    const int lr   = lane & 15;
    const int lg   = lane >> 4;
    const long bB  = (long)blockIdx.x * NB;

    // ---- A-frags: coalesced loads from precomputed frag buffer ----
    h8 Af[TPW][NK];
    {
        const h8* wv = (const h8*)wfm;
#pragma unroll
        for (int tt = 0; tt < TPW; ++tt)
#pragma unroll
            for (int ks = 0; ks < NK; ++ks)
                Af[tt][ks] = wv[((mth * TPW + tt) * NK + ks) * 64 + lane];
    }

    f4 biasF[TPW];
#pragma unroll
    for (int tt = 0; tt < TPW; ++tt)
#pragma unroll
        for (int q = 0; q < 4; ++q) {
            int rr = (mth * TPW + tt) * 16 + lg * 4 + q;
            biasF[tt][q] = (rr < 5 * HID) ? bias[rr] : 0.f;
        }

    // ---- zero sV; stage x for cell (0,0) ----
    for (int idx = tid; idx < H * 16 * SVS; idx += NT) (&sV[0][0][0])[idx] = 0;
    __syncthreads();
    for (int idx = tid; idx < NB * CIN; idx += NT) {
        int b = idx / CIN, c = idx % CIN;
        sV[0][b][swzk(c, b)] = x[(bB + b) * (long)(N * CIN) + c];
    }
    __syncthreads();

    // ---- hoisted epilogue mapping ----
    const bool ep_act = tid < CPB * EPT;
    const int  ep_ci0 = tid / EPT;
    const int  ep_b   = (tid % EPT) / HID;
    const int  ep_j   = tid % HID;
    const int  svl    = swzk(HL0 + ep_j, ep_b);
    const int  svu    = swzk(HU0 + ep_j, ep_b);
    ushort_t* outb = out + (bB + ep_b) * (long)(N * HID) + ep_j;

    // ---- hoisted x-prefetch decomposition ----
    int  xq_ci[XMAX], xq_b[XMAX], xq_off[XMAX];
    long xq_gb[XMAX];
    bool xq_ok[XMAX];
#pragma unroll
    for (int q = 0; q < XMAX; ++q) {
        int idx = tid + q * NT;
        xq_ok[q] = (idx < XTOT);
        int ci = 0, b = 0, c = 0;
        if (xq_ok[q]) { ci = idx / (NB * CIN); int rem = idx % (NB * CIN);
                        b = rem / CIN; c = rem % CIN; }
        xq_ci[q]  = ci; xq_b[q] = b;
        xq_off[q] = swzk(c, b);
        xq_gb[q]  = (bB + b) * (long)(N * CIN) + c;
    }

    // ---- diagonal loop ----
    for (int d = 0; d < 2 * H - 1; ++d) {
        const int i0  = (d > H - 1) ? d - (H - 1) : 0;
        const int i1  = (d < H - 1) ? d : H - 1;
        const int nc  = i1 - i0 + 1;
        const int i0n = (d + 1 > H - 1) ? d + 1 - (H - 1) : 0;
        const int i1n = (d + 1 < H - 1) ? d + 1 : H - 1;
        const int ncn = (d + 1 < 2 * H - 1) ? (i1n - i0n + 1) : 0;
        const int par = d & 1;

        // ===== Phase A: one V read per cell, TPW tile-chains =====
        for (int ci = cs; ci < nc; ci += CSPL) {
            h8 Bh[NK];
#pragma unroll
            for (int ks = 0; ks < NK; ++ks) {
                const int bo = (((ks * 4 + lg) ^ (lr & 7)) << 3);
                Bh[ks] = *(const h8*)&sV[ci][lr][bo];
            }
            f4 acc[TPW];
#pragma unroll
            for (int tt = 0; tt < TPW; ++tt) {
                acc[tt] = __builtin_amdgcn_mfma_f32_16x16x32_f16(
                              Af[tt][0], Bh[0], biasF[tt], 0, 0, 0);
#pragma unroll
                for (int ks = 1; ks < NK; ++ks)
                    acc[tt] = __builtin_amdgcn_mfma_f32_16x16x32_f16(
                                  Af[tt][ks], Bh[ks], acc[tt], 0, 0, 0);
            }
#pragma unroll
            for (int tt = 0; tt < TPW; ++tt) {
                int row4 = (mth * TPW + tt) * 16 + lg * 4;
                if (lr < NB && row4 + 4 <= 5 * HID)
                    *(f4*)&sG[ci][lr][row4] = acc[tt];
            }
        }

        // prefetch next diagonal's x (hides under MFMA)
        ushort_t xval[XMAX];
#pragma unroll
        for (int q = 0; q < XMAX; ++q)
            if (xq_ok[q] && xq_ci[q] < ncn) {
                int ii = i0n + xq_ci[q];
                xval[q] = x[xq_gb[q] + (long)(ii * H + (d + 1 - ii)) * CIN];
            }
        __syncthreads();

        // ===== Phase B: epilogue + scatter h/x into next-diag V =====
        if (ep_act) {
            for (int ci = ep_ci0; ci < nc; ci += CPB) {
                const int i = i0 + ci, jc = d - i;
                const float* gp = &sG[ci][ep_b][ep_j];
                float g0 = gp[0],       g1 = gp[HID],     g2 = gp[2 * HID];
                float g3 = gp[3 * HID], g4 = gp[4 * HID];
                float c_left = (jc > 0) ? sC[par][i][ep_b][ep_j] : 0.f;
                float c_up   = (i  > 0) ? sC[par][i - 1][ep_b][ep_j] : 0.f;
                float cc = sigmoidf_(g1) * c_left + sigmoidf_(g2) * c_up
                         + sigmoidf_(g0) * tanhf_fast(g4);
                float hh = sigmoidf_(g3) * tanhf_fast(cc);
                sC[par ^ 1][i][ep_b][ep_j] = cc;
                ushort_t hv = f2h(hh);
                if (jc + 1 < H) sV[i - i0n][ep_b][svl]     = hv;
                if (i + 1 < H)  sV[i + 1 - i0n][ep_b][svu] = hv;
                outb[(i * H + jc) * HID] = hv;
            }
        }
#pragma unroll
        for (int q = 0; q < XMAX; ++q)
            if (xq_ok[q] && xq_ci[q] < ncn)
                sV[xq_ci[q]][xq_b[q]][xq_off[q]] = xval[q];
        __syncthreads();
    }
}

// ---------- merged prep: all weight fragments (conv2, fc1, m1, m2) ----------
__global__ __launch_bounds__(256) void prep_frags(
    const float* __restrict__ wt,  short* __restrict__ wf,
    const float* __restrict__ w1,  short* __restrict__ wf1,
    const float* __restrict__ m1Wx, const float* __restrict__ m1Wl,
    const float* __restrict__ m1Wu, short* __restrict__ wfm1,
    const float* __restrict__ m2Wx, const float* __restrict__ m2Wl,
    const float* __restrict__ m2Wu, short* __restrict__ wfm2)
{
    int gid = blockIdx.x * 256 + threadIdx.x;
    if (gid < 25600) {                      // ---- conv2 frags ----
        int id = gid;
        int e    = id & 7;
        int lane = (id >> 3) & 63;
        int m    = (id >> 9) & 1;
        int tt   = id >> 10;            // tx*5+ty
        int tx = tt / 5, ty = tt % 5;
        int c = lane & 15, kg = lane >> 4;
        int oc = m * 16 + c, ic = kg * 8 + e;
        float wv = (oc < 30 && ic < 20)
                 ? wt[((oc * 20 + ic) * 5 + ty) * 5 + tx] : 0.f;
        ushort_t wh = f2h(wv);
        ushort_t wl = f2h(wv - h2f(wh));
        wf[(((tt * 2 + m) * 2 + 0) * 64 + lane) * 8 + e] = (short)wh;
        wf[(((tt * 2 + m) * 2 + 1) * 64 + lane) * 8 + e] = (short)wl;
    } else if (gid < 25600 + 143360) {      // ---- fc1 frags ----
        int id = gid - 25600;
        int e    = id & 7;
        int r    = id >> 3;
        int lane = r & 63;  r >>= 6;
        int h    = r & 1;   r >>= 1;
        int ks   = r % 20;
        int m    = r / 20;
        int o  = m * 16 + (lane & 15);
        int kp = ks * 32 + (lane >> 4) * 8 + e;
        int pix = kp / 40, hid = kp % 40;
        float wv = (o < 100) ? w1[o * 640 + hid * 16 + pix] : 0.f;
        ushort_t wh = f2h(wv);
        ushort_t v  = h ? f2h(wv - h2f(wh)) : wh;
        wf1[id] = (short)v;
    } else if (gid < 25600 + 143360 + 7168) {   // ---- m1 frags ----
        // HID=20, CIN=10, TPW=7, NK=2, NWM=1; HL0=10, HU0=30
        int id = gid - (25600 + 143360);
        int e    = id & 7;
        int lane = (id >> 3) & 63;
        int r    = id >> 9;
        int ks   = r & 1;
        int tt   = r >> 1;              // 0..6
        int rg = tt * 16 + (lane & 15);
        int k  = ks * 32 + (lane >> 4) * 8 + e;
        float wv = 0.f;
        if (rg < 100) {
            if (k < 10)       wv = m1Wx[rg * 10 + k];
            else if (k < 30)  wv = m1Wl[rg * 20 + (k - 10)];
            else if (k < 50)  wv = m1Wu[rg * 20 + (k - 30)];
        }
        wfm1[id] = (short)f2h(wv);
    } else if (gid < 25600 + 143360 + 7168 + 30720) {  // ---- m2 frags ----
        // HID=40, CIN=30, TPW=5, NK=4, NWM=3; HL0=30, HU0=70
        int id = gid - (25600 + 143360 + 7168);
        int e    = id & 7;
        int lane = (id >> 3) & 63;
        int r    = id >> 9;             // 0..59 = (mth*5+tt)*4+ks
        int ks   = r & 3;
        int q    = r >> 2;              // 0..14
        int tt   = q % 5;
        int mth  = q / 5;
        int rg = (mth * 5 + tt) * 16 + (lane & 15);
        int k  = ks * 32 + (lane >> 4) * 8 + e;
        float wv = 0.f;
        if (rg < 200) {
            if (k < 30)        wv = m2Wx[rg * 30 + k];
            else if (k < 70)   wv = m2Wl[rg * 40 + (k - 30)];
            else if (k < 110)  wv = m2Wu[rg * 40 + (k - 70)];
        }
        wfm2[id] = (short)f2h(wv);
    }
}

// ---------- conv2 via tap-decomposed MFMA, fp16 input, 16 images/block ----
// in COMPACT fp16 [B,144,20]; wf fp16 wh/wl frags; out fp16 [B,16,30].
__global__ __launch_bounds__(320, 2) void conv2_mfma(
    const ushort_t* __restrict__ in, const short* __restrict__ wf,
    const float* __restrict__ bias, ushort_t* __restrict__ out)
{
    constexpr int NIMG = 16;
    __shared__ ushort_t sImg[2][144][40];     // fp16; k 0..19 real, 20..39 zero
    __shared__ float    sPart[5][2][4][16][20];
    __shared__ float    sB[30];

    const int tid  = threadIdx.x;
    const int lane = tid & 63;
    const int wid  = tid >> 6;          // = tx
    const int c    = lane & 15;
    const int kg   = lane >> 4;
    const long b0  = (long)blockIdx.x * NIMG;

    const h8* wfv = (const h8*)wf;
    h8 Awh[5][2], Awl[5][2];
#pragma unroll
    for (int ty = 0; ty < 5; ++ty)
#pragma unroll
        for (int m = 0; m < 2; ++m) {
            int base = (((wid * 5 + ty) * 2 + m) * 2) * 64 + lane;
            Awh[ty][m] = wfv[base];
            Awl[ty][m] = wfv[base + 64];
        }

    // zero channel pads (both buffers, once)
    for (int idx = tid; idx < 2 * 144 * 20; idx += 320) {
        int bb = idx / (144 * 20);
        int r  = idx % (144 * 20);
        sImg[bb][r / 20][20 + r % 20] = 0;
    }
    if (tid < 30) sB[tid] = bias[tid];

    // stage image 0: 720 uint2 (4 ushorts each; 20%4==0 -> no pos crossing)
    {
        const ushort_t* p = in + b0 * 2880;
        uint2 u0 = *(const uint2*)(p + 4 * tid);
        uint2 u1 = *(const uint2*)(p + 4 * (tid + 320));
        uint2 u2 = {0, 0};
        if (tid < 80) u2 = *(const uint2*)(p + 4 * (tid + 640));
        {
            int g = 4 * tid;          *(uint2*)&sImg[0][g / 20][g % 20] = u0;
            g = 4 * (tid + 320);      *(uint2*)&sImg[0][g / 20][g % 20] = u1;
            if (tid < 80) { g = 4 * (tid + 640);
                            *(uint2*)&sImg[0][g / 20][g % 20] = u2; }
        }
    }
    __syncthreads();

    const int y0 = c >> 3, x = c & 7;
    for (int img = 0; img < NIMG; ++img) {
        const int cb = img & 1;
        uint2 u0, u1, u2;
        const bool have = (img + 1 < NIMG);
        if (have) {
            const ushort_t* p = in + (b0 + img + 1) * 2880;
            u0 = *(const uint2*)(p + 4 * tid);
            u1 = *(const uint2*)(p + 4 * (tid + 320));
            if (tid < 80) u2 = *(const uint2*)(p + 4 * (tid + 640));
        }
        // main: 4 pixel tiles; 4 independent chains (2 m-tiles x wh/wl)
#pragma unroll
        for (int p4 = 0; p4 < 4; ++p4) {
            const int pos = (2 * p4 + y0) * 12 + x + wid;
            const ushort_t* bh = &sImg[cb][pos][kg * 8];
            f4 aH0 = {0.f,0.f,0.f,0.f}, aL0 = {0.f,0.f,0.f,0.f};
            f4 aH1 = {0.f,0.f,0.f,0.f}, aL1 = {0.f,0.f,0.f,0.f};
#pragma unroll
            for (int ks = 0; ks < 5; ++ks) {
                h8 Bh = *(const h8*)(bh + ks * 12 * 40);
                aH0 = __builtin_amdgcn_mfma_f32_16x16x32_f16(Awh[ks][0], Bh, aH0, 0, 0, 0);
                aL0 = __builtin_amdgcn_mfma_f32_16x16x32_f16(Awl[ks][0], Bh, aL0, 0, 0, 0);
                aH1 = __builtin_amdgcn_mfma_f32_16x16x32_f16(Awh[ks][1], Bh, aH1, 0, 0, 0);
                aL1 = __builtin_amdgcn_mfma_f32_16x16x32_f16(Awl[ks][1], Bh, aL1, 0, 0, 0);
            }
            f4 c0 = aH0 + aL0;
            f4 c1 = aH1 + aL1;
            *(f4*)&sPart[wid][0][p4][c][kg * 4] = c0;
            *(f4*)&sPart[wid][1][p4][c][kg * 4] = c1;
        }
        if (have) {
            int g = 4 * tid;          *(uint2*)&sImg[cb ^ 1][g / 20][g % 20] = u0;
            g = 4 * (tid + 320);      *(uint2*)&sImg[cb ^ 1][g / 20][g % 20] = u1;
            if (tid < 80) { g = 4 * (tid + 640);
                            *(uint2*)&sImg[cb ^ 1][g / 20][g % 20] = u2; }
        }
        __syncthreads();
        // fused cross-wave sum + bias + 2x2 maxpool + tanh
        for (int idx = tid; idx < 480; idx += 320) {
            int pix = idx / 30, oc = idx % 30;
            int m = oc >> 4, r = oc & 15;
            int py = pix >> 2, px = pix & 3;
            float vmax = -1e30f;
#pragma unroll
            for (int dy = 0; dy < 2; ++dy)
#pragma unroll
                for (int dx = 0; dx < 2; ++dx) {
                    int n = (2 * py + dy) * 8 + 2 * px + dx;
                    float s = 0.f;
#pragma unroll
                    for (int w = 0; w < 5; ++w)
                        s += sPart[w][m][n >> 4][n & 15][r];
                    vmax = fmaxf(vmax, s);
                }
            out[(b0 + img) * 480 + idx] = f2h(tanhf_fast(vmax + sB[oc]));
        }
        __syncthreads();
    }
}

// ---------- fused fc1(640->100)+tanh + fc2(100->10) + softmax ----------
// in COMPACT fp16 [B,640]; wf1 fp16 wh/wl frags; out fp32 [B,10].
__global__ __launch_bounds__(448) void fc_fused(
    const ushort_t* __restrict__ in, const short* __restrict__ wf1,
    const float* __restrict__ b1, const float* __restrict__ w2,
    const float* __restrict__ b2, float* __restrict__ out)
{
    constexpr int XS = 648;      // padded row stride (ushorts)
    __shared__ ushort_t sX[16][XS];
    __shared__ float    sG[16][116];
    __shared__ float    sF[16][101];
    __shared__ float    sW2[1000];
    __shared__ float    sB2[10];
    __shared__ float    sL[16][12];

    const int tid  = threadIdx.x;
    const int lane = tid & 63;
    const int wid  = tid >> 6;
    const int lr   = lane & 15;
    const int lg   = lane >> 4;
    const long b0  = (long)blockIdx.x * 16;

    // stage x tile: 2560 uint2 (4 ushorts; 640%4==0 -> no row crossing)
    for (int idx = tid; idx < 2560; idx += 448) {
        int flat = idx * 4;
        int row = flat / 640, col = flat % 640;
        *(uint2*)&sX[row][col] =
            *(const uint2*)(in + (b0 + row) * 640 + col);
    }
    for (int idx = tid; idx < 1000; idx += 448) sW2[idx] = w2[idx];
    if (tid < 10) sB2[tid] = b2[tid];

    f4 biasF;
#pragma unroll
    for (int q = 0; q < 4; ++q) {
        int rr = wid * 16 + lg * 4 + q;
        biasF[q] = (rr < 100) ? b1[rr] : 0.f;
    }
    __syncthreads();

    {
        const h8* wfv = (const h8*)wf1;
        f4 hh = biasF, ll = {0.f, 0.f, 0.f, 0.f};
#pragma unroll
        for (int ks = 0; ks < 20; ++ks) {
            int base = ((wid * 20 + ks) * 2) * 64 + lane;
            h8 Awh = wfv[base];
            h8 Awl = wfv[base + 64];
            h8 Bh  = *(const h8*)&sX[lr][ks * 32 + lg * 8];
            hh = __builtin_amdgcn_mfma_f32_16x16x32_f16(Awh, Bh, hh, 0, 0, 0);
            ll = __builtin_amdgcn_mfma_f32_16x16x32_f16(Awl, Bh, ll, 0, 0, 0);
        }
        f4 acc = hh + ll;
        *(f4*)&sG[lr][wid * 16 + lg * 4] = acc;
    }
    __syncthreads();

    for (int idx = tid; idx < 1600; idx += 448) {
        int bb = idx / 100, o = idx % 100;
        sF[bb][o] = tanhf_fast(sG[bb][o]);
    }
    __syncthreads();

    if (tid < 160) {
        int o2 = tid >> 4, bb = tid & 15;
        const float* wr = &sW2[o2 * 100];
        float acc = sB2[o2];
        for (int k = 0; k < 100; ++k) acc += sF[bb][k] * wr[k];
        sL[bb][o2] = acc;
    }
    __syncthreads();

    if (tid < 16) {
        float lg10[10];
#pragma unroll
        for (int o = 0; o < 10; ++o) lg10[o] = sL[tid][o];
        float m = lg10[0];
#pragma unroll
        for (int o = 1; o < 10; ++o) m = fmaxf(m, lg10[o]);
        float s = 0.f;
#pragma unroll
        for (int o = 0; o < 10; ++o) { lg10[o] = __expf(lg10[o] - m); s += lg10[o]; }
        float inv = fast_rcp(s);
        float* ob = out + (b0 + tid) * 10;
#pragma unroll
        for (int o = 0; o < 10; ++o) ob[o] = lg10[o] * inv;
    }
}

extern "C" void kernel_launch(void* const* d_in, const int* in_sizes, int n_in,
                              void* d_out, int out_size, void* d_ws, size_t ws_size,
                              hipStream_t stream)
{
    const float* x    = (const float*)d_in[0];
    const float* c1w  = (const float*)d_in[1];
    const float* c1b  = (const float*)d_in[2];
    const float* m1Wx = (const float*)d_in[3];
    const float* m1Wl = (const float*)d_in[4];
    const float* m1Wu = (const float*)d_in[5];
    const float* m1b  = (const float*)d_in[6];
    const float* c2w  = (const float*)d_in[7];
    const float* c2b  = (const float*)d_in[8];
    const float* m2Wx = (const float*)d_in[9];
    const float* m2Wl = (const float*)d_in[10];
    const float* m2Wu = (const float*)d_in[11];
    const float* m2b  = (const float*)d_in[12];
    const float* f1w  = (const float*)d_in[13];
    const float* f1b  = (const float*)d_in[14];
    const float* f2w  = (const float*)d_in[15];
    const float* f2b  = (const float*)d_in[16];
    float* outp = (float*)d_out;

    char* ws = (char*)d_ws;
    ushort_t* a1 = (ushort_t*)ws;                  // [B,144,10] fp16 11.8 MB
    ushort_t* h1 = (ushort_t*)(ws + 23592960);     // [B,144,20] fp16 11.8 MB
    ushort_t* a2 = a1;                             // [B,16,30] fp16
    ushort_t* h2 = h1;                             // [B,640] fp16 reuse
    short* wfrag  = (short*)(ws + 50331648);       // conv2 frags
    short* wfrag1 = (short*)(ws + 51380224);       // fc1 frags
    short* wfm1   = (short*)(ws + 52428800);       // m1 frags
    short* wfm2   = (short*)(ws + 53477376);       // m2 frags

    prep_frags<<<808, 256, 0, stream>>>(c2w, wfrag, f1w, wfrag1,
                                        m1Wx, m1Wl, m1Wu, wfm1,
                                        m2Wx, m2Wl, m2Wu, wfm2);
    conv1_pool_tanh<<<2304, 256, 0, stream>>>(x, c1w, c1b, a1);
    // m1: H=12, HID=20, CIN=10, KV=64, NK=2, NWM=1, CSPL=12, TPW=7, NB=16
    mdlstm_f16<12, 20, 10, 64, 2, 1, 12, 7, 16><<<256, 768, 0, stream>>>(
        a1, wfm1, m1b, h1);
    conv2_mfma<<<256, 320, 0, stream>>>(h1, wfrag, c2b, a2);
    // m2: H=4, HID=40, CIN=30, KV=128, NK=4, NWM=3, CSPL=4, TPW=5, NB=16
    mdlstm_f16<4, 40, 30, 128, 4, 3, 4, 5, 16><<<256, 768, 0, stream>>>(
        a2, wfm2, m2b, h2);
    fc_fused<<<256, 448, 0, stream>>>(h2, wfrag1, f1b, f2w, f2b, outp);
}

// Round 21
// 144.606 us; speedup vs baseline: 1.5450x; 1.0350x over previous
//
#include <hip/hip_runtime.h>
#include <hip/hip_bf16.h>

typedef __attribute__((ext_vector_type(8))) short sh8;
typedef __attribute__((ext_vector_type(8))) _Float16 h8;
typedef __attribute__((ext_vector_type(4))) float f4;
typedef unsigned short ushort_t;
typedef unsigned int uint_t;

// ---------- fast transcendentals (fp32) ----------
__device__ __forceinline__ float fast_rcp(float x) {
    return __builtin_amdgcn_rcpf(x);
}
__device__ __forceinline__ float sigmoidf_(float x) {
    return fast_rcp(1.f + __expf(-x));
}
__device__ __forceinline__ float tanhf_fast(float x) {
    float ax = fabsf(x);
    float e  = __expf(-2.f * ax);
    float t  = (1.f - e) * fast_rcp(1.f + e);
    return copysignf(t, x);
}

// ---------- fp16 helpers ----------
__device__ __forceinline__ ushort_t f2h(float x) {
    union { _Float16 f; ushort_t u; } cv;
    cv.f = (_Float16)x;
    return cv.u;
}
__device__ __forceinline__ float h2f(ushort_t u) {
    union { _Float16 f; ushort_t u; } cv;
    cv.u = u;
    return (float)cv.f;
}
// XOR swizzle of 8-ushort blocks within a batch-row of sV
__device__ __forceinline__ int swzk(int k, int b) {
    return ((((k >> 3) ^ (b & 7)) << 3) | (k & 7));
}

// ---------- conv1 (1->10, 5x5 VALID) + maxpool2 + tanh ----------
// x: [B,784] as 28x28, out COMPACT fp16: [B,144,10]  (proven)
__global__ __launch_bounds__(256) void conv1_pool_tanh(
    const float* __restrict__ x, const float* __restrict__ w,
    const float* __restrict__ bias, ushort_t* __restrict__ out)
{
    __shared__ float sw[250];
    __shared__ float sb[10];
    int t = threadIdx.x;
    if (t < 250) sw[t] = w[t];
    if (t < 10)  sb[t] = bias[t];
    __syncthreads();

    int gp  = blockIdx.x * 256 + t;
    int b   = gp / 144;
    int pix = gp % 144;
    int py = pix / 12, px = pix % 12;

    const float* img = x + (long)b * 784 + (2 * py) * 28 + 2 * px;
    float r[6][6];
#pragma unroll
    for (int ry = 0; ry < 6; ++ry)
#pragma unroll
        for (int rx = 0; rx < 6; ++rx)
            r[ry][rx] = img[ry * 28 + rx];

    ushort_t* ob = out + ((long)b * 144 + pix) * 10;
    for (int oc = 0; oc < 10; ++oc) {
        float a0 = 0.f, a1 = 0.f, a2 = 0.f, a3 = 0.f;
#pragma unroll
        for (int ky = 0; ky < 5; ++ky)
#pragma unroll
            for (int kx = 0; kx < 5; ++kx) {
                float wv = sw[oc * 25 + ky * 5 + kx];
                a0 += wv * r[ky][kx];
                a1 += wv * r[ky][kx + 1];
                a2 += wv * r[ky + 1][kx];
                a3 += wv * r[ky + 1][kx + 1];
            }
        float m = fmaxf(fmaxf(a0, a1), fmaxf(a2, a3)) + sb[oc];
        ob[oc] = f2h(tanhf_fast(m));
    }
}

// ---------- diagonal-wavefront fp16-MFMA 2D-LSTM, fat waves (m1) ----------
template<int H, int HID, int CIN, int KV, int NK, int NWM, int CSPL, int TPW, int NB>
__global__ __launch_bounds__(NWM * CSPL * 64) void mdlstm_f16(
    const ushort_t* __restrict__ x, const short* __restrict__ wfm,
    const float* __restrict__ bias, ushort_t* __restrict__ out)
{
    constexpr int N    = H * H;
    constexpr int NT   = NWM * CSPL * 64;
    constexpr int HL0  = CIN, HU0 = CIN + HID;
    constexpr int SVS  = KV;
    constexpr int GS   = 5 * HID;
    constexpr int XTOT = H * NB * CIN;
    constexpr int XMAX = (XTOT + NT - 1) / NT;
    constexpr int EPT  = NB * HID;
    constexpr int CPB  = NT / EPT;
    static_assert(NWM * TPW * 16 >= 5 * HID, "tiles cover gate rows");
    static_assert(KV >= CIN + 2 * HID, "K covers V");
    static_assert(CPB >= 1, "epilogue coverage");

    __shared__ ushort_t sV[H][16][SVS];
    __shared__ float    sG[H][NB][GS];
    __shared__ float    sC[2][H][NB][HID];

    const int tid  = threadIdx.x;
    const int lane = tid & 63;
    const int wid  = tid >> 6;
    const int mth  = wid % NWM;
    const int cs   = wid / NWM;
    const int lr   = lane & 15;
    const int lg   = lane >> 4;
    const long bB  = (long)blockIdx.x * NB;

    h8 Af[TPW][NK];
    {
        const h8* wv = (const h8*)wfm;
#pragma unroll
        for (int tt = 0; tt < TPW; ++tt)
#pragma unroll
            for (int ks = 0; ks < NK; ++ks)
                Af[tt][ks] = wv[((mth * TPW + tt) * NK + ks) * 64 + lane];
    }

    f4 biasF[TPW];
#pragma unroll
    for (int tt = 0; tt < TPW; ++tt)
#pragma unroll
        for (int q = 0; q < 4; ++q) {
            int rr = (mth * TPW + tt) * 16 + lg * 4 + q;
            biasF[tt][q] = (rr < 5 * HID) ? bias[rr] : 0.f;
        }

    for (int idx = tid; idx < H * 16 * SVS; idx += NT) (&sV[0][0][0])[idx] = 0;
    __syncthreads();
    for (int idx = tid; idx < NB * CIN; idx += NT) {
        int b = idx / CIN, c = idx % CIN;
        sV[0][b][swzk(c, b)] = x[(bB + b) * (long)(N * CIN) + c];
    }
    __syncthreads();

    const bool ep_act = tid < CPB * EPT;
    const int  ep_ci0 = tid / EPT;
    const int  ep_b   = (tid % EPT) / HID;
    const int  ep_j   = tid % HID;
    const int  svl    = swzk(HL0 + ep_j, ep_b);
    const int  svu    = swzk(HU0 + ep_j, ep_b);
    ushort_t* outb = out + (bB + ep_b) * (long)(N * HID) + ep_j;

    int  xq_ci[XMAX], xq_b[XMAX], xq_off[XMAX];
    long xq_gb[XMAX];
    bool xq_ok[XMAX];
#pragma unroll
    for (int q = 0; q < XMAX; ++q) {
        int idx = tid + q * NT;
        xq_ok[q] = (idx < XTOT);
        int ci = 0, b = 0, c = 0;
        if (xq_ok[q]) { ci = idx / (NB * CIN); int rem = idx % (NB * CIN);
                        b = rem / CIN; c = rem % CIN; }
        xq_ci[q]  = ci; xq_b[q] = b;
        xq_off[q] = swzk(c, b);
        xq_gb[q]  = (bB + b) * (long)(N * CIN) + c;
    }

    for (int d = 0; d < 2 * H - 1; ++d) {
        const int i0  = (d > H - 1) ? d - (H - 1) : 0;
        const int i1  = (d < H - 1) ? d : H - 1;
        const int nc  = i1 - i0 + 1;
        const int i0n = (d + 1 > H - 1) ? d + 1 - (H - 1) : 0;
        const int i1n = (d + 1 < H - 1) ? d + 1 : H - 1;
        const int ncn = (d + 1 < 2 * H - 1) ? (i1n - i0n + 1) : 0;
        const int par = d & 1;

        for (int ci = cs; ci < nc; ci += CSPL) {
            h8 Bh[NK];
#pragma unroll
            for (int ks = 0; ks < NK; ++ks) {
                const int bo = (((ks * 4 + lg) ^ (lr & 7)) << 3);
                Bh[ks] = *(const h8*)&sV[ci][lr][bo];
            }
            f4 acc[TPW];
#pragma unroll
            for (int tt = 0; tt < TPW; ++tt) {
                acc[tt] = __builtin_amdgcn_mfma_f32_16x16x32_f16(
                              Af[tt][0], Bh[0], biasF[tt], 0, 0, 0);
#pragma unroll
                for (int ks = 1; ks < NK; ++ks)
                    acc[tt] = __builtin_amdgcn_mfma_f32_16x16x32_f16(
                                  Af[tt][ks], Bh[ks], acc[tt], 0, 0, 0);
            }
#pragma unroll
            for (int tt = 0; tt < TPW; ++tt) {
                int row4 = (mth * TPW + tt) * 16 + lg * 4;
                if (lr < NB && row4 + 4 <= 5 * HID)
                    *(f4*)&sG[ci][lr][row4] = acc[tt];
            }
        }

        ushort_t xval[XMAX];
#pragma unroll
        for (int q = 0; q < XMAX; ++q)
            if (xq_ok[q] && xq_ci[q] < ncn) {
                int ii = i0n + xq_ci[q];
                xval[q] = x[xq_gb[q] + (long)(ii * H + (d + 1 - ii)) * CIN];
            }
        __syncthreads();

        if (ep_act) {
            for (int ci = ep_ci0; ci < nc; ci += CPB) {
                const int i = i0 + ci, jc = d - i;
                const float* gp = &sG[ci][ep_b][ep_j];
                float g0 = gp[0],       g1 = gp[HID],     g2 = gp[2 * HID];
                float g3 = gp[3 * HID], g4 = gp[4 * HID];
                float c_left = (jc > 0) ? sC[par][i][ep_b][ep_j] : 0.f;
                float c_up   = (i  > 0) ? sC[par][i - 1][ep_b][ep_j] : 0.f;
                float cc = sigmoidf_(g1) * c_left + sigmoidf_(g2) * c_up
                         + sigmoidf_(g0) * tanhf_fast(g4);
                float hh = sigmoidf_(g3) * tanhf_fast(cc);
                sC[par ^ 1][i][ep_b][ep_j] = cc;
                ushort_t hv = f2h(hh);
                if (jc + 1 < H) sV[i - i0n][ep_b][svl]     = hv;
                if (i + 1 < H)  sV[i + 1 - i0n][ep_b][svu] = hv;
                outb[(i * H + jc) * HID] = hv;
            }
        }
#pragma unroll
        for (int q = 0; q < XMAX; ++q)
            if (xq_ok[q] && xq_ci[q] < ncn)
                sV[xq_ci[q]][xq_b[q]][xq_off[q]] = xval[q];
        __syncthreads();
    }
}

// ---------- fused m2 (2D-LSTM) + fc1 + fc2 + softmax ----------
// a2 fp16 [B,16,30]; wfm2 fp16 frags; wf1 fp16 wh/wl frags; out fp32 [B,10].
// Phase 1 = m2 scan (r18 code, h -> LDS sH2). Phase 2 = fc (r18 code,
// reads sH2; scratch carved from dead sG region).
__global__ __launch_bounds__(768) void m2fc_fused(
    const ushort_t* __restrict__ x, const short* __restrict__ wfm,
    const float* __restrict__ bias, const short* __restrict__ wf1,
    const float* __restrict__ b1, const float* __restrict__ w2,
    const float* __restrict__ b2, float* __restrict__ out)
{
    constexpr int H = 4, HID = 40, CIN = 30, KV = 128, NK = 4;
    constexpr int NWM = 3, CSPL = 4, TPW = 5, NB = 16;
    constexpr int N    = 16;
    constexpr int NT   = 768;
    constexpr int HL0  = CIN, HU0 = CIN + HID;
    constexpr int SVS  = KV;
    constexpr int GS   = 5 * HID;          // 200
    constexpr int XTOT = H * NB * CIN;     // 1920
    constexpr int XMAX = 3;
    constexpr int EPT  = NB * HID;         // 640
    constexpr int XS   = 648;

    __shared__ ushort_t sV[H][16][SVS];      // 16 KB
    __shared__ float    sG[H][NB][GS];       // 51.2 KB (fc scratch later)
    __shared__ float    sC[2][H][NB][HID];   // 20.5 KB
    __shared__ ushort_t sH2[16][XS];         // 20.7 KB (h2 hand-off)

    const int tid  = threadIdx.x;
    const int lane = tid & 63;
    const int wid  = tid >> 6;
    const int mth  = wid % NWM;
    const int cs   = wid / NWM;
    const int lr   = lane & 15;
    const int lg   = lane >> 4;
    const long bB  = (long)blockIdx.x * NB;

    // ======== Phase 1: m2 scan (verbatim r18) ========
    h8 Af[TPW][NK];
    {
        const h8* wv = (const h8*)wfm;
#pragma unroll
        for (int tt = 0; tt < TPW; ++tt)
#pragma unroll
            for (int ks = 0; ks < NK; ++ks)
                Af[tt][ks] = wv[((mth * TPW + tt) * NK + ks) * 64 + lane];
    }
    f4 biasF[TPW];
#pragma unroll
    for (int tt = 0; tt < TPW; ++tt)
#pragma unroll
        for (int q = 0; q < 4; ++q) {
            int rr = (mth * TPW + tt) * 16 + lg * 4 + q;
            biasF[tt][q] = (rr < 5 * HID) ? bias[rr] : 0.f;
        }

    for (int idx = tid; idx < H * 16 * SVS; idx += NT) (&sV[0][0][0])[idx] = 0;
    __syncthreads();
    for (int idx = tid; idx < NB * CIN; idx += NT) {
        int b = idx / CIN, c = idx % CIN;
        sV[0][b][swzk(c, b)] = x[(bB + b) * (long)(N * CIN) + c];
    }
    __syncthreads();

    const bool ep_act = tid < EPT;
    const int  ep_b   = (tid % EPT) / HID;
    const int  ep_j   = tid % HID;
    const int  svl    = swzk(HL0 + ep_j, ep_b);
    const int  svu    = swzk(HU0 + ep_j, ep_b);

    int  xq_ci[XMAX], xq_b[XMAX], xq_off[XMAX];
    long xq_gb[XMAX];
    bool xq_ok[XMAX];
#pragma unroll
    for (int q = 0; q < XMAX; ++q) {
        int idx = tid + q * NT;
        xq_ok[q] = (idx < XTOT);
        int ci = 0, b = 0, c = 0;
        if (xq_ok[q]) { ci = idx / (NB * CIN); int rem = idx % (NB * CIN);
                        b = rem / CIN; c = rem % CIN; }
        xq_ci[q]  = ci; xq_b[q] = b;
        xq_off[q] = swzk(c, b);
        xq_gb[q]  = (bB + b) * (long)(N * CIN) + c;
    }

    for (int d = 0; d < 2 * H - 1; ++d) {
        const int i0  = (d > H - 1) ? d - (H - 1) : 0;
        const int i1  = (d < H - 1) ? d : H - 1;
        const int nc  = i1 - i0 + 1;
        const int i0n = (d + 1 > H - 1) ? d + 1 - (H - 1) : 0;
        const int i1n = (d + 1 < H - 1) ? d + 1 : H - 1;
        const int ncn = (d + 1 < 2 * H - 1) ? (i1n - i0n + 1) : 0;
        const int par = d & 1;

        for (int ci = cs; ci < nc; ci += CSPL) {
            h8 Bh[NK];
#pragma unroll
            for (int ks = 0; ks < NK; ++ks) {
                const int bo = (((ks * 4 + lg) ^ (lr & 7)) << 3);
                Bh[ks] = *(const h8*)&sV[ci][lr][bo];
            }
            f4 acc[TPW];
#pragma unroll
            for (int tt = 0; tt < TPW; ++tt) {
                acc[tt] = __builtin_amdgcn_mfma_f32_16x16x32_f16(
                              Af[tt][0], Bh[0], biasF[tt], 0, 0, 0);
#pragma unroll
                for (int ks = 1; ks < NK; ++ks)
                    acc[tt] = __builtin_amdgcn_mfma_f32_16x16x32_f16(
                                  Af[tt][ks], Bh[ks], acc[tt], 0, 0, 0);
            }
#pragma unroll
            for (int tt = 0; tt < TPW; ++tt) {
                int row4 = (mth * TPW + tt) * 16 + lg * 4;
                if (lr < NB && row4 + 4 <= 5 * HID)
                    *(f4*)&sG[ci][lr][row4] = acc[tt];
            }
        }

        ushort_t xval[XMAX];
#pragma unroll
        for (int q = 0; q < XMAX; ++q)
            if (xq_ok[q] && xq_ci[q] < ncn) {
                int ii = i0n + xq_ci[q];
                xval[q] = x[xq_gb[q] + (long)(ii * H + (d + 1 - ii)) * CIN];
            }
        __syncthreads();

        if (ep_act) {
            for (int ci = 0; ci < nc; ++ci) {
                const int i = i0 + ci, jc = d - i;
                const float* gp = &sG[ci][ep_b][ep_j];
                float g0 = gp[0],       g1 = gp[HID],     g2 = gp[2 * HID];
                float g3 = gp[3 * HID], g4 = gp[4 * HID];
                float c_left = (jc > 0) ? sC[par][i][ep_b][ep_j] : 0.f;
                float c_up   = (i  > 0) ? sC[par][i - 1][ep_b][ep_j] : 0.f;
                float cc = sigmoidf_(g1) * c_left + sigmoidf_(g2) * c_up
                         + sigmoidf_(g0) * tanhf_fast(g4);
                float hh = sigmoidf_(g3) * tanhf_fast(cc);
                sC[par ^ 1][i][ep_b][ep_j] = cc;
                ushort_t hv = f2h(hh);
                if (jc + 1 < H) sV[i - i0n][ep_b][svl]     = hv;
                if (i + 1 < H)  sV[i + 1 - i0n][ep_b][svu] = hv;
                sH2[ep_b][(i * H + jc) * HID + ep_j] = hv;   // h2 -> LDS
            }
        }
#pragma unroll
        for (int q = 0; q < XMAX; ++q)
            if (xq_ok[q] && xq_ci[q] < ncn)
                sV[xq_ci[q]][xq_b[q]][xq_off[q]] = xval[q];
        __syncthreads();
    }

    // ======== Phase 2: fc1+tanh + fc2 + softmax (verbatim r18) ========
    // scratch carved from dead sG region (12800 floats available)
    float* scratch = &sG[0][0][0];
    float* fcG = scratch;               // [16][116] = 1856
    float* sF  = scratch + 1856;        // [16][101] = 1616
    float* sW2 = scratch + 3472;        // [1000]
    float* sB2 = scratch + 4472;        // [10]
    float* sL  = scratch + 4482;        // [16][12] = 192

    for (int idx = tid; idx < 1000; idx += NT) sW2[idx] = w2[idx];
    if (tid < 10) sB2[tid] = b2[tid];

    f4 bF;
#pragma unroll
    for (int q = 0; q < 4; ++q) {
        int rr = wid * 16 + lg * 4 + q;
        bF[q] = (rr < 100) ? b1[rr] : 0.f;
    }
    __syncthreads();

    if (wid < 7) {
        const h8* wfv = (const h8*)wf1;
        f4 hh = bF, ll = {0.f, 0.f, 0.f, 0.f};
#pragma unroll
        for (int ks = 0; ks < 20; ++ks) {
            int base = ((wid * 20 + ks) * 2) * 64 + lane;
            h8 Awh = wfv[base];
            h8 Awl = wfv[base + 64];
            h8 Bh  = *(const h8*)&sH2[lr][ks * 32 + lg * 8];
            hh = __builtin_amdgcn_mfma_f32_16x16x32_f16(Awh, Bh, hh, 0, 0, 0);
            ll = __builtin_amdgcn_mfma_f32_16x16x32_f16(Awl, Bh, ll, 0, 0, 0);
        }
        f4 acc = hh + ll;
        *(f4*)&fcG[lr * 116 + wid * 16 + lg * 4] = acc;
    }
    __syncthreads();

    for (int idx = tid; idx < 1600; idx += NT) {
        int bb = idx / 100, o = idx % 100;
        sF[bb * 101 + o] = tanhf_fast(fcG[bb * 116 + o]);
    }
    __syncthreads();

    if (tid < 160) {
        int o2 = tid >> 4, bb = tid & 15;
        const float* wr = &sW2[o2 * 100];
        float acc = sB2[o2];
        for (int k = 0; k < 100; ++k) acc += sF[bb * 101 + k] * wr[k];
        sL[bb * 12 + o2] = acc;
    }
    __syncthreads();

    if (tid < 16) {
        float lg10[10];
#pragma unroll
        for (int o = 0; o < 10; ++o) lg10[o] = sL[tid * 12 + o];
        float m = lg10[0];
#pragma unroll
        for (int o = 1; o < 10; ++o) m = fmaxf(m, lg10[o]);
        float s = 0.f;
#pragma unroll
        for (int o = 0; o < 10; ++o) { lg10[o] = __expf(lg10[o] - m); s += lg10[o]; }
        float inv = fast_rcp(s);
        float* ob = out + (bB + tid) * 10;
#pragma unroll
        for (int o = 0; o < 10; ++o) ob[o] = lg10[o] * inv;
    }
}

// ---------- merged prep: all weight fragments (conv2, fc1, m1, m2) ----------
__global__ __launch_bounds__(256) void prep_frags(
    const float* __restrict__ wt,  short* __restrict__ wf,
    const float* __restrict__ w1,  short* __restrict__ wf1,
    const float* __restrict__ m1Wx, const float* __restrict__ m1Wl,
    const float* __restrict__ m1Wu, short* __restrict__ wfm1,
    const float* __restrict__ m2Wx, const float* __restrict__ m2Wl,
    const float* __restrict__ m2Wu, short* __restrict__ wfm2)
{
    int gid = blockIdx.x * 256 + threadIdx.x;
    if (gid < 25600) {                      // ---- conv2 frags ----
        int id = gid;
        int e    = id & 7;
        int lane = (id >> 3) & 63;
        int m    = (id >> 9) & 1;
        int tt   = id >> 10;            // tx*5+ty
        int tx = tt / 5, ty = tt % 5;
        int c = lane & 15, kg = lane >> 4;
        int oc = m * 16 + c, ic = kg * 8 + e;
        float wv = (oc < 30 && ic < 20)
                 ? wt[((oc * 20 + ic) * 5 + ty) * 5 + tx] : 0.f;
        ushort_t wh = f2h(wv);
        ushort_t wl = f2h(wv - h2f(wh));
        wf[(((tt * 2 + m) * 2 + 0) * 64 + lane) * 8 + e] = (short)wh;
        wf[(((tt * 2 + m) * 2 + 1) * 64 + lane) * 8 + e] = (short)wl;
    } else if (gid < 25600 + 143360) {      // ---- fc1 frags ----
        int id = gid - 25600;
        int e    = id & 7;
        int r    = id >> 3;
        int lane = r & 63;  r >>= 6;
        int h    = r & 1;   r >>= 1;
        int ks   = r % 20;
        int m    = r / 20;
        int o  = m * 16 + (lane & 15);
        int kp = ks * 32 + (lane >> 4) * 8 + e;
        int pix = kp / 40, hid = kp % 40;
        float wv = (o < 100) ? w1[o * 640 + hid * 16 + pix] : 0.f;
        ushort_t wh = f2h(wv);
        ushort_t v  = h ? f2h(wv - h2f(wh)) : wh;
        wf1[id] = (short)v;
    } else if (gid < 25600 + 143360 + 7168) {   // ---- m1 frags ----
        int id = gid - (25600 + 143360);
        int e    = id & 7;
        int lane = (id >> 3) & 63;
        int r    = id >> 9;
        int ks   = r & 1;
        int tt   = r >> 1;              // 0..6
        int rg = tt * 16 + (lane & 15);
        int k  = ks * 32 + (lane >> 4) * 8 + e;
        float wv = 0.f;
        if (rg < 100) {
            if (k < 10)       wv = m1Wx[rg * 10 + k];
            else if (k < 30)  wv = m1Wl[rg * 20 + (k - 10)];
            else if (k < 50)  wv = m1Wu[rg * 20 + (k - 30)];
        }
        wfm1[id] = (short)f2h(wv);
    } else if (gid < 25600 + 143360 + 7168 + 30720) {  // ---- m2 frags ----
        int id = gid - (25600 + 143360 + 7168);
        int e    = id & 7;
        int lane = (id >> 3) & 63;
        int r    = id >> 9;             // (mth*5+tt)*4+ks
        int ks   = r & 3;
        int q    = r >> 2;
        int tt   = q % 5;
        int mth  = q / 5;
        int rg = (mth * 5 + tt) * 16 + (lane & 15);
        int k  = ks * 32 + (lane >> 4) * 8 + e;
        float wv = 0.f;
        if (rg < 200) {
            if (k < 30)        wv = m2Wx[rg * 30 + k];
            else if (k < 70)   wv = m2Wl[rg * 40 + (k - 30)];
            else if (k < 110)  wv = m2Wu[rg * 40 + (k - 70)];
        }
        wfm2[id] = (short)f2h(wv);
    }
}

// ---------- conv2 via tap-decomposed MFMA, fp16 input, 16 images/block ----
__global__ __launch_bounds__(320, 2) void conv2_mfma(
    const ushort_t* __restrict__ in, const short* __restrict__ wf,
    const float* __restrict__ bias, ushort_t* __restrict__ out)
{
    constexpr int NIMG = 16;
    __shared__ ushort_t sImg[2][144][40];
    __shared__ float    sPart[5][2][4][16][20];
    __shared__ float    sB[30];

    const int tid  = threadIdx.x;
    const int lane = tid & 63;
    const int wid  = tid >> 6;          // = tx
    const int c    = lane & 15;
    const int kg   = lane >> 4;
    const long b0  = (long)blockIdx.x * NIMG;

    const h8* wfv = (const h8*)wf;
    h8 Awh[5][2], Awl[5][2];
#pragma unroll
    for (int ty = 0; ty < 5; ++ty)
#pragma unroll
        for (int m = 0; m < 2; ++m) {
            int base = (((wid * 5 + ty) * 2 + m) * 2) * 64 + lane;
            Awh[ty][m] = wfv[base];
            Awl[ty][m] = wfv[base + 64];
        }

    for (int idx = tid; idx < 2 * 144 * 20; idx += 320) {
        int bb = idx / (144 * 20);
        int r  = idx % (144 * 20);
        sImg[bb][r / 20][20 + r % 20] = 0;
    }
    if (tid < 30) sB[tid] = bias[tid];

    {
        const ushort_t* p = in + b0 * 2880;
        uint2 u0 = *(const uint2*)(p + 4 * tid);
        uint2 u1 = *(const uint2*)(p + 4 * (tid + 320));
        uint2 u2 = {0, 0};
        if (tid < 80) u2 = *(const uint2*)(p + 4 * (tid + 640));
        {
            int g = 4 * tid;          *(uint2*)&sImg[0][g / 20][g % 20] = u0;
            g = 4 * (tid + 320);      *(uint2*)&sImg[0][g / 20][g % 20] = u1;
            if (tid < 80) { g = 4 * (tid + 640);
                            *(uint2*)&sImg[0][g / 20][g % 20] = u2; }
        }
    }
    __syncthreads();

    const int y0 = c >> 3, x = c & 7;
    for (int img = 0; img < NIMG; ++img) {
        const int cb = img & 1;
        uint2 u0, u1, u2;
        const bool have = (img + 1 < NIMG);
        if (have) {
            const ushort_t* p = in + (b0 + img + 1) * 2880;
            u0 = *(const uint2*)(p + 4 * tid);
            u1 = *(const uint2*)(p + 4 * (tid + 320));
            if (tid < 80) u2 = *(const uint2*)(p + 4 * (tid + 640));
        }
#pragma unroll
        for (int p4 = 0; p4 < 4; ++p4) {
            const int pos = (2 * p4 + y0) * 12 + x + wid;
            const ushort_t* bh = &sImg[cb][pos][kg * 8];
            f4 aH0 = {0.f,0.f,0.f,0.f}, aL0 = {0.f,0.f,0.f,0.f};
            f4 aH1 = {0.f,0.f,0.f,0.f}, aL1 = {0.f,0.f,0.f,0.f};
#pragma unroll
            for (int ks = 0; ks < 5; ++ks) {
                h8 Bh = *(const h8*)(bh + ks * 12 * 40);
                aH0 = __builtin_amdgcn_mfma_f32_16x16x32_f16(Awh[ks][0], Bh, aH0, 0, 0, 0);
                aL0 = __builtin_amdgcn_mfma_f32_16x16x32_f16(Awl[ks][0], Bh, aL0, 0, 0, 0);
                aH1 = __builtin_amdgcn_mfma_f32_16x16x32_f16(Awh[ks][1], Bh, aH1, 0, 0, 0);
                aL1 = __builtin_amdgcn_mfma_f32_16x16x32_f16(Awl[ks][1], Bh, aL1, 0, 0, 0);
            }
            f4 c0 = aH0 + aL0;
            f4 c1 = aH1 + aL1;
            *(f4*)&sPart[wid][0][p4][c][kg * 4] = c0;
            *(f4*)&sPart[wid][1][p4][c][kg * 4] = c1;
        }
        if (have) {
            int g = 4 * tid;          *(uint2*)&sImg[cb ^ 1][g / 20][g % 20] = u0;
            g = 4 * (tid + 320);      *(uint2*)&sImg[cb ^ 1][g / 20][g % 20] = u1;
            if (tid < 80) { g = 4 * (tid + 640);
                            *(uint2*)&sImg[cb ^ 1][g / 20][g % 20] = u2; }
        }
        __syncthreads();
        for (int idx = tid; idx < 480; idx += 320) {
            int pix = idx / 30, oc = idx % 30;
            int m = oc >> 4, r = oc & 15;
            int py = pix >> 2, px = pix & 3;
            float vmax = -1e30f;
#pragma unroll
            for (int dy = 0; dy < 2; ++dy)
#pragma unroll
                for (int dx = 0; dx < 2; ++dx) {
                    int n = (2 * py + dy) * 8 + 2 * px + dx;
                    float s = 0.f;
#pragma unroll
                    for (int w = 0; w < 5; ++w)
                        s += sPart[w][m][n >> 4][n & 15][r];
                    vmax = fmaxf(vmax, s);
                }
            out[(b0 + img) * 480 + idx] = f2h(tanhf_fast(vmax + sB[oc]));
        }
        __syncthreads();
    }
}

extern "C" void kernel_launch(void* const* d_in, const int* in_sizes, int n_in,
                              void* d_out, int out_size, void* d_ws, size_t ws_size,
                              hipStream_t stream)
{
    const float* x    = (const float*)d_in[0];
    const float* c1w  = (const float*)d_in[1];
    const float* c1b  = (const float*)d_in[2];
    const float* m1Wx = (const float*)d_in[3];
    const float* m1Wl = (const float*)d_in[4];
    const float* m1Wu = (const float*)d_in[5];
    const float* m1b  = (const float*)d_in[6];
    const float* c2w  = (const float*)d_in[7];
    const float* c2b  = (const float*)d_in[8];
    const float* m2Wx = (const float*)d_in[9];
    const float* m2Wl = (const float*)d_in[10];
    const float* m2Wu = (const float*)d_in[11];
    const float* m2b  = (const float*)d_in[12];
    const float* f1w  = (const float*)d_in[13];
    const float* f1b  = (const float*)d_in[14];
    const float* f2w  = (const float*)d_in[15];
    const float* f2b  = (const float*)d_in[16];
    float* outp = (float*)d_out;

    char* ws = (char*)d_ws;
    ushort_t* a1 = (ushort_t*)ws;                  // [B,144,10] fp16 11.8 MB
    ushort_t* h1 = (ushort_t*)(ws + 23592960);     // [B,144,20] fp16 11.8 MB
    ushort_t* a2 = a1;                             // [B,16,30] fp16
    short* wfrag  = (short*)(ws + 50331648);       // conv2 frags
    short* wfrag1 = (short*)(ws + 51380224);       // fc1 frags
    short* wfm1   = (short*)(ws + 52428800);       // m1 frags
    short* wfm2   = (short*)(ws + 53477376);       // m2 frags

    prep_frags<<<808, 256, 0, stream>>>(c2w, wfrag, f1w, wfrag1,
                                        m1Wx, m1Wl, m1Wu, wfm1,
                                        m2Wx, m2Wl, m2Wu, wfm2);
    conv1_pool_tanh<<<2304, 256, 0, stream>>>(x, c1w, c1b, a1);
    // m1: H=12, HID=20, CIN=10, KV=64, NK=2, NWM=1, CSPL=12, TPW=7, NB=16
    mdlstm_f16<12, 20, 10, 64, 2, 1, 12, 7, 16><<<256, 768, 0, stream>>>(
        a1, wfm1, m1b, h1);
    conv2_mfma<<<256, 320, 0, stream>>>(h1, wfrag, c2b, a2);
    // fused m2 + fc1 + fc2 + softmax
    m2fc_fused<<<256, 768, 0, stream>>>(a2, wfm2, m2b, wfrag1,
                                        f1b, f2w, f2b, outp);
}